// Round 10
// baseline (249.211 us; speedup 1.0000x reference)
//
#include <hip/hip_runtime.h>
#include <limits.h>
#include <math.h>
#include <stdint.h>

// Problem constants (fixed by setup_inputs): x[128][262144] fp32, topk=5.
#define BROWS 128
#define NCOLS (256 * 32 * 32)        // 262144 elements per row
#define K 5
#define BPR 32                       // chunks per row -> 4096 chunks total
#define TPB 256
#define CHUNK (NCOLS / BPR)          // 8192 elements per chunk
#define C4 (CHUNK / 4)               // 2048 float4 per chunk
#define F4T (C4 / TPB)               // 8 float4 per thread per chunk
#define WPR (BPR * 4)                // wave-chunks per row = 128
#define SBLK 1024                    // stream blocks (4 per CU, 16 waves/CU)
#define CPB ((BROWS * BPR) / SBLK)   // 4 chunks per block
#define NFLAG 16                     // flagged-chunk capacity (expect ~5)
#define CAP 256                      // candidate capacity (expect ~10)

typedef float v4f __attribute__((ext_vector_type(4)));

// ---- packed 64-bit candidate key: [sortable_f32 : 32][~index : 32] ----
// bigger key == better (value desc, then index asc) -> matches jax.lax.top_k.
__device__ __forceinline__ uint64_t make_key(float f, uint32_t idx) {
    uint32_t u = __float_as_uint(f);
    u = (u & 0x80000000u) ? ~u : (u | 0x80000000u);   // monotone fp32 -> u32
    return ((uint64_t)u << 32) | (uint32_t)(~idx);
}
__device__ __forceinline__ uint32_t key_idx(uint64_t k) { return ~(uint32_t)k; }

#define KEY_NEG_INF 0x007FFFFF00000000ULL  // make_key(-INFINITY, 0xFFFFFFFF)

__device__ __forceinline__ void insert5(uint64_t (&key)[K], uint64_t c) {
    if (c > key[K - 1]) {
        key[K - 1] = c;
#pragma unroll
        for (int s = K - 1; s > 0; --s) {
            if (key[s] > key[s - 1]) {
                uint64_t t = key[s]; key[s] = key[s - 1]; key[s - 1] = t;
            }
        }
    }
}

__device__ __forceinline__ void wave_reduce5(uint64_t (&key)[K]) {
#pragma unroll
    for (int off = 1; off < 64; off <<= 1) {
        uint64_t ok[K];
#pragma unroll
        for (int k = 0; k < K; ++k)
            ok[k] = __shfl_xor((unsigned long long)key[k], off, 64);
#pragma unroll
        for (int k = 0; k < K; ++k) insert5(key, ok[k]);
    }
}

// float top-5 insert (values only, for the threshold)
__device__ __forceinline__ void insert5f(float (&v)[K], float c) {
    if (c > v[K - 1]) {
        v[K - 1] = c;
#pragma unroll
        for (int s = K - 1; s > 0; --s) {
            if (v[s] > v[s - 1]) { float t = v[s]; v[s] = v[s - 1]; v[s - 1] = t; }
        }
    }
}

// K1: dependency-free stream (m13-copy shape). Per iteration: one float4 load,
// one INDEPENDENT constant store (never waits), one fmax into a per-chunk
// accumulator. No shfl, no cross-lane op, no wave-wide vmcnt drain anywhere in
// the stream -- the only waits are the compiler's counted vmcnt before each
// fmax. All wave reduces deferred to a once-per-wave epilogue. This removes
// the per-16KB full-drain that every previous (2.45 TB/s) variant shared.
__global__ __launch_bounds__(TPB) void wta_stream(const float* __restrict__ x,
                                                  float* __restrict__ out,
                                                  float* __restrict__ wmax) {
    const int b = blockIdx.x;
    const int t = threadIdx.x;
    const int lane = t & 63, w = t >> 6;
    const int c0 = b * CPB;                 // first chunk of this block
    const float4* __restrict__ x4 = (const float4*)x;
    float4* __restrict__ o4 = (float4*)out;
    const float4 z = {0.f, 0.f, 0.f, 0.f};
    const size_t base = (size_t)c0 * C4 + t;

    float m[CPB];
#pragma unroll
    for (int ch = 0; ch < CPB; ++ch) m[ch] = -INFINITY;

#pragma unroll
    for (int ch = 0; ch < CPB; ++ch) {
#pragma unroll
        for (int j = 0; j < F4T; ++j) {
            const size_t idx = base + (size_t)ch * C4 + j * TPB;
            const float4 v = x4[idx];
            o4[idx] = z;                    // constant store: no dependency
            m[ch] = fmaxf(m[ch], fmaxf(fmaxf(v.x, v.y), fmaxf(v.z, v.w)));
        }
    }

    // epilogue: per-chunk wave butterfly max + one scalar store each
#pragma unroll
    for (int ch = 0; ch < CPB; ++ch) {
        float M = m[ch];
#pragma unroll
        for (int off = 1; off < 64; off <<= 1)
            M = fmaxf(M, __shfl_xor(M, off, 64));
        if (lane == 0) wmax[(c0 + ch) * 4 + w] = M;
    }
}

// K2: one block per row. T = 5th-largest of the row's 128 wave-maxes. Since T
// is the min of 5 actual elements, V5(row) >= T, and every true top-5 element
// sits in a chunk with wmax >= T. Rescan only those (~5) chunks (cache-hot),
// collect all elements >= T as u64 keys, exact top-5, scatter five 1.0 stores.
__global__ __launch_bounds__(TPB) void wta_finish(const float* __restrict__ x,
                                                  const float* __restrict__ wmax,
                                                  float* __restrict__ out) {
    const int row = blockIdx.x;
    const int t = threadIdx.x;
    const float* __restrict__ wm = wmax + row * WPR;

    __shared__ float sT;
    __shared__ int nflag, ncand;
    __shared__ int flaglist[NFLAG];
    __shared__ uint64_t cand[CAP];

    if (t == 0) { nflag = 0; ncand = 0; }
    __syncthreads();

    // ---- threshold: top-5 of 128 wave-maxes (first wave only) ----
    if (t < 64) {
        float v[K];
#pragma unroll
        for (int k = 0; k < K; ++k) v[k] = -INFINITY;
        insert5f(v, wm[t]);
        insert5f(v, wm[t + 64]);
#pragma unroll
        for (int off = 1; off < 64; off <<= 1) {
            float ov[K];
#pragma unroll
            for (int k = 0; k < K; ++k) ov[k] = __shfl_xor(v[k], off, 64);
#pragma unroll
            for (int k = 0; k < K; ++k) insert5f(v, ov[k]);
        }
        if (t == 0) sT = v[K - 1];
    }
    __syncthreads();
    const float T = sT;

    // ---- flag chunks with wmax >= T (expect ~5) ----
    if (t < WPR && wm[t] >= T) {
        const int s = atomicAdd(&nflag, 1);
        if (s < NFLAG) flaglist[s] = t;
    }
    __syncthreads();
    const int nf = min(nflag, NFLAG);

    // ---- rescan flagged chunks (coalesced, cache-hot), collect survivors ----
    const int lane = t & 63, jj = t >> 6;
    for (int f = 0; f < nf; ++f) {
        const int wid = flaglist[f];
        const int gbk = wid >> 2;          // chunk within row
        const int w   = wid & 3;           // wave within chunk
        const float4* __restrict__ xb =
            (const float4*)(x + (size_t)row * NCOLS + (size_t)gbk * CHUNK);
#pragma unroll
        for (int rep = 0; rep < 2; ++rep) {
            const int j = jj + rep * 4;
            const int f4pos = w * 64 + lane + j * TPB;
            const float4 d = xb[f4pos];
            const float vs[4] = {d.x, d.y, d.z, d.w};
#pragma unroll
            for (int c = 0; c < 4; ++c) {
                if (vs[c] >= T) {
                    const int s = atomicAdd(&ncand, 1);
                    if (s < CAP)
                        cand[s] = make_key(vs[c],
                                           (uint32_t)gbk * CHUNK + (uint32_t)f4pos * 4u + c);
                }
            }
        }
    }
    __syncthreads();

    // ---- exact top-5 of survivors, scatter ones ----
    if (t < 64) {
        const int n = min(ncand, CAP);
        uint64_t key[K];
#pragma unroll
        for (int k = 0; k < K; ++k) key[k] = KEY_NEG_INF;
        for (int i = t; i < n; i += 64) insert5(key, cand[i]);
        wave_reduce5(key);
        if (t == 0) {
#pragma unroll
            for (int k = 0; k < K; ++k)
                if (key[k] != KEY_NEG_INF)
                    out[(size_t)row * NCOLS + key_idx(key[k])] = 1.0f;
        }
    }
}

extern "C" void kernel_launch(void* const* d_in, const int* in_sizes, int n_in,
                              void* d_out, int out_size, void* d_ws, size_t ws_size,
                              hipStream_t stream) {
    const float* x = (const float*)d_in[0];
    float* out = (float*)d_out;

    // ws layout: wmax (4096 chunks * 4 waves f32 = 64 KiB)
    float* wmax = (float*)d_ws;

    wta_stream<<<SBLK, TPB, 0, stream>>>(x, out, wmax);
    wta_finish<<<BROWS, TPB, 0, stream>>>(x, wmax, out);
}

// Round 11
// 239.944 us; speedup vs baseline: 1.0386x; 1.0386x over previous
//
#include <hip/hip_runtime.h>
#include <limits.h>
#include <math.h>
#include <stdint.h>

// Problem constants (fixed by setup_inputs): x[128][262144] fp32, topk=5.
#define BROWS 128
#define NCOLS (256 * 32 * 32)        // 262144 elements per row
#define K 5
#define TPB 256
#define SPANS_PER_ROW 1024           // 256-float spans per row
#define SPAN 256                     // floats per span (64 float4)
#define SCAN_BLOCKS 2048
#define SCAN_ITERS 16                // 8.39M float4 / (2048*256)
#define STRIDE4 (SCAN_BLOCKS * TPB)  // 524288 float4 grid stride
#define NFLAG 32                     // flagged-span capacity (expect ~5)
#define CAP 256                      // candidate capacity (expect ~10)

// ---- packed 64-bit candidate key: [sortable_f32 : 32][~index : 32] ----
// bigger key == better (value desc, then index asc) -> matches jax.lax.top_k.
__device__ __forceinline__ uint64_t make_key(float f, uint32_t idx) {
    uint32_t u = __float_as_uint(f);
    u = (u & 0x80000000u) ? ~u : (u | 0x80000000u);   // monotone fp32 -> u32
    return ((uint64_t)u << 32) | (uint32_t)(~idx);
}
__device__ __forceinline__ uint32_t key_idx(uint64_t k) { return ~(uint32_t)k; }

#define KEY_NEG_INF 0x007FFFFF00000000ULL  // make_key(-INFINITY, 0xFFFFFFFF)

__device__ __forceinline__ void insert5(uint64_t (&key)[K], uint64_t c) {
    if (c > key[K - 1]) {
        key[K - 1] = c;
#pragma unroll
        for (int s = K - 1; s > 0; --s) {
            if (key[s] > key[s - 1]) {
                uint64_t t = key[s]; key[s] = key[s - 1]; key[s - 1] = t;
            }
        }
    }
}

__device__ __forceinline__ void wave_reduce5(uint64_t (&key)[K]) {
#pragma unroll
    for (int off = 1; off < 64; off <<= 1) {
        uint64_t ok[K];
#pragma unroll
        for (int k = 0; k < K; ++k)
            ok[k] = __shfl_xor((unsigned long long)key[k], off, 64);
#pragma unroll
        for (int k = 0; k < K; ++k) insert5(key, ok[k]);
    }
}

// float top-5 insert (values only, for the threshold)
__device__ __forceinline__ void insert5f(float (&v)[K], float c) {
    if (c > v[K - 1]) {
        v[K - 1] = c;
#pragma unroll
        for (int s = K - 1; s > 0; --s) {
            if (v[s] > v[s - 1]) { float t = v[s]; v[s] = v[s - 1]; v[s - 1] = t; }
        }
    }
}

// K1: PURE-READ scan, m13-copy shape (the write is delegated to hipMemsetAsync
// -> rocclr fillBufferAligned, measured 6.6 TB/s in this very harness).
// Grid-stride: 16 fully-unrolled strided loads per thread into 16 independent
// accumulators; zero cross-lane ops in the stream; all wave reduces + span-max
// stores (0.5 MB total) deferred to the epilogue. Directly measurable: this is
// the first pure-read kernel of the session that will show its own dur_us.
// Span (wave,iter) covers float4 [waveid*64 + i*STRIDE4, +64) -- 256 floats,
// always within one row; global span id = waveid + i*8192.
__global__ __launch_bounds__(TPB) void wta_scan(const float* __restrict__ x,
                                                float* __restrict__ wmax) {
    const int t = threadIdx.x;
    const int g = blockIdx.x * TPB + t;
    const int lane = t & 63, w = t >> 6;
    const int waveid = blockIdx.x * 4 + w;      // 0..8191
    const float4* __restrict__ x4 = (const float4*)x;

    float m[SCAN_ITERS];
#pragma unroll
    for (int i = 0; i < SCAN_ITERS; ++i) {
        const float4 v = x4[(size_t)g + (size_t)i * STRIDE4];
        m[i] = fmaxf(fmaxf(v.x, v.y), fmaxf(v.z, v.w));
    }

    // epilogue: per-iteration span max across the wave, one scalar store each
#pragma unroll
    for (int i = 0; i < SCAN_ITERS; ++i) {
        float M = m[i];
#pragma unroll
        for (int off = 1; off < 64; off <<= 1)
            M = fmaxf(M, __shfl_xor(M, off, 64));
        if (lane == 0) wmax[waveid + i * (SCAN_BLOCKS * 4)] = M;
    }
}

// K2: one block per row. T = 5th-largest of the row's 1024 span-maxes. T is
// the min of 5 actual elements in 5 distinct spans => V5(row) >= T => every
// true top-5 element is >= T and lives in a span with spanmax >= T. Rescan
// the ~5 flagged 256-float spans (1 float4/lane, 4 spans across 4 waves),
// collect survivors as u64 keys, exact top-5, scatter five 1.0 stores.
__global__ __launch_bounds__(TPB) void wta_finish(const float* __restrict__ x,
                                                  const float* __restrict__ wmax,
                                                  float* __restrict__ out) {
    const int row = blockIdx.x;
    const int t = threadIdx.x;
    const float* __restrict__ wm = wmax + (size_t)row * SPANS_PER_ROW;

    __shared__ float sT;
    __shared__ int nflag, ncand;
    __shared__ int flaglist[NFLAG];
    __shared__ uint64_t cand[CAP];

    if (t == 0) { nflag = 0; ncand = 0; }
    __syncthreads();

    // ---- threshold: top-5 of 1024 span-maxes (first wave, 16/lane) ----
    if (t < 64) {
        float v[K];
#pragma unroll
        for (int k = 0; k < K; ++k) v[k] = -INFINITY;
#pragma unroll
        for (int i = 0; i < SPANS_PER_ROW / 64; ++i) insert5f(v, wm[t + i * 64]);
#pragma unroll
        for (int off = 1; off < 64; off <<= 1) {
            float ov[K];
#pragma unroll
            for (int k = 0; k < K; ++k) ov[k] = __shfl_xor(v[k], off, 64);
#pragma unroll
            for (int k = 0; k < K; ++k) insert5f(v, ov[k]);
        }
        if (t == 0) sT = v[K - 1];
    }
    __syncthreads();
    const float T = sT;

    // ---- flag spans with spanmax >= T (expect ~5) ----
    for (int s = t; s < SPANS_PER_ROW; s += TPB) {
        if (wm[s] >= T) {
            const int p = atomicAdd(&nflag, 1);
            if (p < NFLAG) flaglist[p] = s;
        }
    }
    __syncthreads();
    const int nf = min(nflag, NFLAG);

    // ---- rescan flagged spans: 1 float4 per lane, 4 spans in parallel ----
    const int lane = t & 63, w4 = t >> 6;
    for (int f = w4; f < nf; f += 4) {
        const int sp = flaglist[f];
        const float4 d =
            ((const float4*)(x + (size_t)row * NCOLS + (size_t)sp * SPAN))[lane];
        const float vs[4] = {d.x, d.y, d.z, d.w};
#pragma unroll
        for (int c = 0; c < 4; ++c) {
            if (vs[c] >= T) {
                const int p = atomicAdd(&ncand, 1);
                if (p < CAP)
                    cand[p] = make_key(vs[c],
                                       (uint32_t)sp * SPAN + (uint32_t)lane * 4u + c);
            }
        }
    }
    __syncthreads();

    // ---- exact top-5 of survivors, scatter ones ----
    if (t < 64) {
        const int n = min(ncand, CAP);
        uint64_t key[K];
#pragma unroll
        for (int k = 0; k < K; ++k) key[k] = KEY_NEG_INF;
        for (int i = t; i < n; i += 64) insert5(key, cand[i]);
        wave_reduce5(key);
        if (t == 0) {
#pragma unroll
            for (int k = 0; k < K; ++k)
                if (key[k] != KEY_NEG_INF)
                    out[(size_t)row * NCOLS + key_idx(key[k])] = 1.0f;
        }
    }
}

extern "C" void kernel_launch(void* const* d_in, const int* in_sizes, int n_in,
                              void* d_out, int out_size, void* d_ws, size_t ws_size,
                              hipStream_t stream) {
    const float* x = (const float*)d_in[0];
    float* out = (float*)d_out;

    // ws layout: wmax (131072 span-maxes f32 = 512 KiB)
    float* wmax = (float*)d_ws;

    // Zero-fill via the runtime's fillBufferAligned path -- measured at
    // 6.6 TB/s in this harness (vs ~2.5 TB/s for every in-kernel variant).
    // hipMemsetAsync is stream-ordered and graph-capture-safe (the harness's
    // own reset() uses it).
    hipMemsetAsync(d_out, 0, (size_t)out_size, stream);

    wta_scan<<<SCAN_BLOCKS, TPB, 0, stream>>>(x, wmax);
    wta_finish<<<BROWS, TPB, 0, stream>>>(x, wmax, out);
}

// Round 12
// 226.366 us; speedup vs baseline: 1.1009x; 1.0600x over previous
//
#include <hip/hip_runtime.h>
#include <limits.h>
#include <math.h>
#include <stdint.h>

// Problem constants (fixed by setup_inputs): x[128][262144] fp32, topk=5.
#define BROWS 128
#define NCOLS (256 * 32 * 32)        // 262144 elements per row
#define K 5
#define TPB 256
#define SPANS_PER_ROW 1024           // 256-float spans per row
#define SPAN 256                     // floats per span (64 float4)
#define SCAN_BLOCKS 2048
#define SCAN_ITERS 16                // 8.39M float4 / (2048*256)
#define STRIDE4 (SCAN_BLOCKS * TPB)  // 524288 float4 grid stride
#define NFLAG 32                     // flagged-span capacity (expect ~5)
#define CAP 256                      // candidate capacity (expect ~10)

typedef float v4f __attribute__((ext_vector_type(4)));

// ---- packed 64-bit candidate key: [sortable_f32 : 32][~index : 32] ----
// bigger key == better (value desc, then index asc) -> matches jax.lax.top_k.
__device__ __forceinline__ uint64_t make_key(float f, uint32_t idx) {
    uint32_t u = __float_as_uint(f);
    u = (u & 0x80000000u) ? ~u : (u | 0x80000000u);   // monotone fp32 -> u32
    return ((uint64_t)u << 32) | (uint32_t)(~idx);
}
__device__ __forceinline__ uint32_t key_idx(uint64_t k) { return ~(uint32_t)k; }

#define KEY_NEG_INF 0x007FFFFF00000000ULL  // make_key(-INFINITY, 0xFFFFFFFF)

__device__ __forceinline__ void insert5(uint64_t (&key)[K], uint64_t c) {
    if (c > key[K - 1]) {
        key[K - 1] = c;
#pragma unroll
        for (int s = K - 1; s > 0; --s) {
            if (key[s] > key[s - 1]) {
                uint64_t t = key[s]; key[s] = key[s - 1]; key[s - 1] = t;
            }
        }
    }
}

__device__ __forceinline__ void wave_reduce5(uint64_t (&key)[K]) {
#pragma unroll
    for (int off = 1; off < 64; off <<= 1) {
        uint64_t ok[K];
#pragma unroll
        for (int k = 0; k < K; ++k)
            ok[k] = __shfl_xor((unsigned long long)key[k], off, 64);
#pragma unroll
        for (int k = 0; k < K; ++k) insert5(key, ok[k]);
    }
}

// float top-5 insert (values only, for the threshold)
__device__ __forceinline__ void insert5f(float (&v)[K], float c) {
    if (c > v[K - 1]) {
        v[K - 1] = c;
#pragma unroll
        for (int s = K - 1; s > 0; --s) {
            if (v[s] > v[s - 1]) { float t = v[s]; v[s] = v[s - 1]; v[s - 1] = t; }
        }
    }
}

// K1: PURE-READ scan with NON-TEMPORAL loads. Identical to the R11 scan
// (grid-stride m13 shape, 16 independent loads/thread, reduces deferred to
// epilogue) except loads are __builtin_nontemporal_load. Theory under test:
// the harness's ~1 GiB poison fills leave the 256 MiB LLC full of dirty
// lines; cached read misses ALLOCATE in LLC and force dirty writebacks --
// a hidden write stream that halves effective read BW. nt loads skip LLC
// allocation -> no forced evictions -> reads stream at HBM rate. Caching x
// is worthless anyway (finish rescans only ~640 KB).
__global__ __launch_bounds__(TPB) void wta_scan(const float* __restrict__ x,
                                                float* __restrict__ wmax) {
    const int t = threadIdx.x;
    const int g = blockIdx.x * TPB + t;
    const int lane = t & 63, w = t >> 6;
    const int waveid = blockIdx.x * 4 + w;      // 0..8191
    const v4f* __restrict__ x4 = (const v4f*)x;

    float m[SCAN_ITERS];
#pragma unroll
    for (int i = 0; i < SCAN_ITERS; ++i) {
        const v4f v = __builtin_nontemporal_load(&x4[(size_t)g + (size_t)i * STRIDE4]);
        m[i] = fmaxf(fmaxf(v.x, v.y), fmaxf(v.z, v.w));
    }

    // epilogue: per-iteration span max across the wave, one scalar store each
#pragma unroll
    for (int i = 0; i < SCAN_ITERS; ++i) {
        float M = m[i];
#pragma unroll
        for (int off = 1; off < 64; off <<= 1)
            M = fmaxf(M, __shfl_xor(M, off, 64));
        if (lane == 0) wmax[waveid + i * (SCAN_BLOCKS * 4)] = M;
    }
}

// K2: one block per row. T = 5th-largest of the row's 1024 span-maxes. T is
// the min of 5 actual elements in 5 distinct spans => V5(row) >= T => every
// true top-5 element is >= T and lives in a span with spanmax >= T. Rescan
// the ~5 flagged 256-float spans (1 float4/lane, 4 spans across 4 waves),
// collect survivors as u64 keys, exact top-5, scatter five 1.0 stores.
__global__ __launch_bounds__(TPB) void wta_finish(const float* __restrict__ x,
                                                  const float* __restrict__ wmax,
                                                  float* __restrict__ out) {
    const int row = blockIdx.x;
    const int t = threadIdx.x;
    const float* __restrict__ wm = wmax + (size_t)row * SPANS_PER_ROW;

    __shared__ float sT;
    __shared__ int nflag, ncand;
    __shared__ int flaglist[NFLAG];
    __shared__ uint64_t cand[CAP];

    if (t == 0) { nflag = 0; ncand = 0; }
    __syncthreads();

    // ---- threshold: top-5 of 1024 span-maxes (first wave, 16/lane) ----
    if (t < 64) {
        float v[K];
#pragma unroll
        for (int k = 0; k < K; ++k) v[k] = -INFINITY;
#pragma unroll
        for (int i = 0; i < SPANS_PER_ROW / 64; ++i) insert5f(v, wm[t + i * 64]);
#pragma unroll
        for (int off = 1; off < 64; off <<= 1) {
            float ov[K];
#pragma unroll
            for (int k = 0; k < K; ++k) ov[k] = __shfl_xor(v[k], off, 64);
#pragma unroll
            for (int k = 0; k < K; ++k) insert5f(v, ov[k]);
        }
        if (t == 0) sT = v[K - 1];
    }
    __syncthreads();
    const float T = sT;

    // ---- flag spans with spanmax >= T (expect ~5) ----
    for (int s = t; s < SPANS_PER_ROW; s += TPB) {
        if (wm[s] >= T) {
            const int p = atomicAdd(&nflag, 1);
            if (p < NFLAG) flaglist[p] = s;
        }
    }
    __syncthreads();
    const int nf = min(nflag, NFLAG);

    // ---- rescan flagged spans: 1 float4 per lane, 4 spans in parallel ----
    const int lane = t & 63, w4 = t >> 6;
    for (int f = w4; f < nf; f += 4) {
        const int sp = flaglist[f];
        const float4 d =
            ((const float4*)(x + (size_t)row * NCOLS + (size_t)sp * SPAN))[lane];
        const float vs[4] = {d.x, d.y, d.z, d.w};
#pragma unroll
        for (int c = 0; c < 4; ++c) {
            if (vs[c] >= T) {
                const int p = atomicAdd(&ncand, 1);
                if (p < CAP)
                    cand[p] = make_key(vs[c],
                                       (uint32_t)sp * SPAN + (uint32_t)lane * 4u + c);
            }
        }
    }
    __syncthreads();

    // ---- exact top-5 of survivors, scatter ones ----
    if (t < 64) {
        const int n = min(ncand, CAP);
        uint64_t key[K];
#pragma unroll
        for (int k = 0; k < K; ++k) key[k] = KEY_NEG_INF;
        for (int i = t; i < n; i += 64) insert5(key, cand[i]);
        wave_reduce5(key);
        if (t == 0) {
#pragma unroll
            for (int k = 0; k < K; ++k)
                if (key[k] != KEY_NEG_INF)
                    out[(size_t)row * NCOLS + key_idx(key[k])] = 1.0f;
        }
    }
}

extern "C" void kernel_launch(void* const* d_in, const int* in_sizes, int n_in,
                              void* d_out, int out_size, void* d_ws, size_t ws_size,
                              hipStream_t stream) {
    const float* x = (const float*)d_in[0];
    float* out = (float*)d_out;

    // ws layout: wmax (131072 span-maxes f32 = 512 KiB)
    float* wmax = (float*)d_ws;

    // Zero-fill via the runtime's fillBufferAligned path (measured 6.6 TB/s
    // in this harness). Stream-ordered, graph-capture-safe.
    hipMemsetAsync(d_out, 0, (size_t)out_size, stream);

    wta_scan<<<SCAN_BLOCKS, TPB, 0, stream>>>(x, wmax);
    wta_finish<<<BROWS, TPB, 0, stream>>>(x, wmax, out);
}